// Round 8
// baseline (346.054 us; speedup 1.0000x reference)
//
#include <hip/hip_runtime.h>
#include <hip/hip_bf16.h>
#include <math.h>

#define N_NODES 50000

typedef __attribute__((ext_vector_type(8))) short short8;   // 8 bf16 = 4 VGPRs
typedef __attribute__((ext_vector_type(4))) float f32x4;

static __device__ __forceinline__ float b2f(unsigned int u16) {
    union { unsigned int i; float f; } c; c.i = u16 << 16; return c.f;
}
static __device__ __forceinline__ unsigned int fbits(float f) {
    union { float f; unsigned int i; } c; c.f = f; return c.i;
}
static __device__ __forceinline__ unsigned short f2b_rne(float f) {
    unsigned int u = fbits(f);
    u += 0x7fff + ((u >> 16) & 1);
    return (unsigned short)(u >> 16);
}

// ---------------- fused prep: cast x, cast+transpose weights, histogram ----------------

__global__ __launch_bounds__(256) void k_prep(
        const float* __restrict__ x, unsigned short* __restrict__ xb,
        const float* __restrict__ W1l, const float* __restrict__ W1r, unsigned short* __restrict__ wt1,
        const float* __restrict__ W2l, const float* __restrict__ W2r, unsigned short* __restrict__ wt2,
        const int* __restrict__ dst, int E, int* __restrict__ counts) {
    const int CX = (N_NODES * 128 / 4) / 256;   // 6250
    int b = blockIdx.x, t = threadIdx.x;
    if (b < CX) {
        int i = b * 256 + t;
        float4 v = *(const float4*)(x + (size_t)i * 4);
        ushort4 o;
        o.x = f2b_rne(v.x); o.y = f2b_rne(v.y); o.z = f2b_rne(v.z); o.w = f2b_rne(v.w);
        *(ushort4*)(xb + (size_t)i * 4) = o;
    } else if (b < CX + 256) {
        int i = (b - CX) * 256 + t;             // 65536: WT1[n][k]
        int n = i >> 8, k = i & 255;
        float v = (k < 128) ? W1l[(size_t)k * 256 + n] : W1r[(size_t)(k - 128) * 256 + n];
        wt1[(size_t)n * 256 + k] = f2b_rne(v);
    } else if (b < CX + 320) {
        int i = (b - CX - 256) * 256 + t;       // 16384: WT2[n][k]
        int n = i >> 9, k = i & 511;
        float v = (k < 256) ? W2l[(size_t)k * 32 + n] : W2r[(size_t)(k - 256) * 32 + n];
        wt2[(size_t)n * 512 + k] = f2b_rne(v);
    } else {
        int e = (b - CX - 320) * 256 + t;
        if (e < E) atomicAdd(&counts[dst[e]], 1);
    }
}

// ---------------- single-pass exclusive scan (decoupled lookback) ----------------
// 196 blocks (all co-resident on 256 CUs -> no dispatch-order assumption needed).
// Block publishes its total via device-scope atomicExch; wave 0 polls all
// predecessors (wave-parallel) and sums. pub[] must be zeroed beforehand.

#define SCAN_FLAG 0x40000000

__global__ __launch_bounds__(256) void k_scan_fused(const int* __restrict__ counts,
        int* __restrict__ rowptr, int* __restrict__ cursor, int* __restrict__ pub,
        int n, int E) {
    __shared__ int tmp[256];
    __shared__ int pfx;
    int b = blockIdx.x, t = threadIdx.x;
    int i = b * 256 + t;
    int v = (i < n) ? counts[i] : 0;
    tmp[t] = v;
    __syncthreads();
    for (int off = 1; off < 256; off <<= 1) {
        int add = (t >= off) ? tmp[t - off] : 0;
        __syncthreads();
        tmp[t] += add;
        __syncthreads();
    }
    if (t == 255) atomicExch(&pub[b], SCAN_FLAG | tmp[255]);   // publish block total
    if (t < 64) {
        int acc = 0;
        for (int base = 0; base < b; base += 64) {
            int idx = base + t;
            if (idx < b) {
                int val;
                do { val = atomicOr(&pub[idx], 0); } while (!(val & SCAN_FLAG));
                acc += val & (SCAN_FLAG - 1);
            }
        }
#pragma unroll
        for (int off = 32; off >= 1; off >>= 1) acc += __shfl_xor(acc, off);
        if (t == 0) pfx = acc;
    }
    __syncthreads();
    int ex = pfx + tmp[t] - v;
    if (i < n) { rowptr[i] = ex; cursor[i] = ex; }
    if (i == 0) rowptr[n] = E;
}

// ---------------- scatter: NT loads + NT stores, 8 grid-strided edges/thread ----------------
// NT store avoids L2 write-allocate of randomly-addressed 4B stores whose 64B
// lines are shared across XCDs and never combine (R6: 52 MB HBM writes vs 3.2 MB buffer).

__global__ __launch_bounds__(256) void k_scatter(const int* __restrict__ src,
        const int* __restrict__ dst, int E,
        int* __restrict__ cursor, int* __restrict__ esrc) {
    int tid = blockIdx.x * 256 + threadIdx.x;
    int S = gridDim.x * 256;
    int d[8], s[8], e[8];
#pragma unroll
    for (int u = 0; u < 8; ++u) {
        e[u] = tid + u * S;
        d[u] = 0; s[u] = 0;
        if (e[u] < E) {
            d[u] = __builtin_nontemporal_load(&dst[e[u]]);
            s[u] = __builtin_nontemporal_load(&src[e[u]]);
        }
    }
#pragma unroll
    for (int u = 0; u < 8; ++u) {
        if (e[u] < E) {
            int p = atomicAdd(&cursor[d[u]], 1);
            __builtin_nontemporal_store(s[u], &esrc[p]);
        }
    }
}

// ---------------- seg_max layer 1: uint4 gathers, 4 edges per load ----------------

__global__ __launch_bounds__(256) void k_seg_max1(const unsigned short* __restrict__ feat,
        const int* __restrict__ rowptr, const int* __restrict__ esrc,
        unsigned short* __restrict__ out) {
    int w = threadIdx.x >> 6, t = threadIdx.x & 63;
    int n = blockIdx.x * 4 + w;
    int lane16 = t & 15, sub = t >> 4;
    int beg = rowptr[n], end = rowptr[n + 1];
    float m[8];
#pragma unroll
    for (int k = 0; k < 8; ++k) m[k] = -INFINITY;
    for (int base = beg; base < end; base += 64) {
        int cnt = min(64, end - base);
        int vidx = (base + t < end) ? __builtin_nontemporal_load(&esrc[base + t]) : 0;
        for (int j = 0; j < cnt; j += 16) {
            uint4 v[4];
#pragma unroll
            for (int u = 0; u < 4; ++u) {
                int e = min(j + 4 * u + sub, cnt - 1);
                int s = __shfl(vidx, e);
                v[u] = *(const uint4*)(feat + (size_t)s * 128 + lane16 * 8);
            }
#pragma unroll
            for (int u = 0; u < 4; ++u) {
                m[0] = fmaxf(m[0], b2f(v[u].x & 0xffff));
                m[1] = fmaxf(m[1], b2f(v[u].x >> 16));
                m[2] = fmaxf(m[2], b2f(v[u].y & 0xffff));
                m[3] = fmaxf(m[3], b2f(v[u].y >> 16));
                m[4] = fmaxf(m[4], b2f(v[u].z & 0xffff));
                m[5] = fmaxf(m[5], b2f(v[u].z >> 16));
                m[6] = fmaxf(m[6], b2f(v[u].w & 0xffff));
                m[7] = fmaxf(m[7], b2f(v[u].w >> 16));
            }
        }
    }
#pragma unroll
    for (int k = 0; k < 8; ++k) {
        m[k] = fmaxf(m[k], __shfl_xor(m[k], 16));
        m[k] = fmaxf(m[k], __shfl_xor(m[k], 32));
        if (beg == end) m[k] = 0.f;
    }
    if (sub == 0) {
        uint4 p;
        p.x = (fbits(m[0]) >> 16) | (fbits(m[1]) & 0xffff0000u);
        p.y = (fbits(m[2]) >> 16) | (fbits(m[3]) & 0xffff0000u);
        p.z = (fbits(m[4]) >> 16) | (fbits(m[5]) & 0xffff0000u);
        p.w = (fbits(m[6]) >> 16) | (fbits(m[7]) & 0xffff0000u);
        *(uint4*)(out + (size_t)n * 128 + lane16 * 8) = p;
    }
}

// ---------------- seg_max layer 2: 8 uint4 gathers in flight ----------------

__global__ __launch_bounds__(256) void k_seg_max2(const unsigned short* __restrict__ feat,
        const int* __restrict__ rowptr, const int* __restrict__ esrc,
        unsigned short* __restrict__ out) {
    int w = threadIdx.x >> 6, t = threadIdx.x & 63;
    int n = blockIdx.x * 4 + w;
    int lane32 = t & 31, half = t >> 5;
    int beg = rowptr[n], end = rowptr[n + 1];
    float m[8];
#pragma unroll
    for (int k = 0; k < 8; ++k) m[k] = -INFINITY;
    for (int base = beg; base < end; base += 64) {
        int cnt = min(64, end - base);
        int vidx = (base + t < end) ? __builtin_nontemporal_load(&esrc[base + t]) : 0;
        for (int j = 0; j < cnt; j += 16) {
            uint4 v[8];
#pragma unroll
            for (int u = 0; u < 8; ++u) {
                int e = min(j + 2 * u + half, cnt - 1);
                int s = __shfl(vidx, e);
                v[u] = *(const uint4*)(feat + (size_t)s * 256 + lane32 * 8);
            }
#pragma unroll
            for (int u = 0; u < 8; ++u) {
                m[0] = fmaxf(m[0], b2f(v[u].x & 0xffff));
                m[1] = fmaxf(m[1], b2f(v[u].x >> 16));
                m[2] = fmaxf(m[2], b2f(v[u].y & 0xffff));
                m[3] = fmaxf(m[3], b2f(v[u].y >> 16));
                m[4] = fmaxf(m[4], b2f(v[u].z & 0xffff));
                m[5] = fmaxf(m[5], b2f(v[u].z >> 16));
                m[6] = fmaxf(m[6], b2f(v[u].w & 0xffff));
                m[7] = fmaxf(m[7], b2f(v[u].w >> 16));
            }
        }
    }
#pragma unroll
    for (int k = 0; k < 8; ++k) {
        m[k] = fmaxf(m[k], __shfl_xor(m[k], 32));
        if (beg == end) m[k] = 0.f;
    }
    if (half == 0) {
        uint4 p;
        p.x = (fbits(m[0]) >> 16) | (fbits(m[1]) & 0xffff0000u);
        p.y = (fbits(m[2]) >> 16) | (fbits(m[3]) & 0xffff0000u);
        p.z = (fbits(m[4]) >> 16) | (fbits(m[5]) & 0xffff0000u);
        p.w = (fbits(m[6]) >> 16) | (fbits(m[7]) & 0xffff0000u);
        *(uint4*)(out + (size_t)n * 256 + lane32 * 8) = p;
    }
}

// ---------------- layer 1 MFMA GEMM ----------------

__global__ __launch_bounds__(256) void k_lin1_mfma(
        const unsigned short* __restrict__ A0, const unsigned short* __restrict__ A1,
        const unsigned short* __restrict__ WT, const float* __restrict__ bias,
        unsigned short* __restrict__ H, int M) {
    __shared__ short As[128 * 40];
    __shared__ short Bs[128 * 40];

    int tid = threadIdx.x;
    int m0 = blockIdx.y * 128, n0 = blockIdx.x * 128;
    int L = tid & 63, wv = tid >> 6;
    int wr = wv >> 1, wc = wv & 1;
    int lane16 = L & 15, q = L >> 4;

    f32x4 acc[4][4];
#pragma unroll
    for (int i = 0; i < 4; ++i)
#pragma unroll
        for (int j = 0; j < 4; ++j) acc[i][j] = (f32x4){0.f, 0.f, 0.f, 0.f};

    for (int k0 = 0; k0 < 256; k0 += 32) {
        const unsigned short* Abase = (k0 < 128) ? A0 : A1;
        int kc = k0 & 127;
#pragma unroll
        for (int s = tid; s < 512; s += 256) {
            int m = s >> 2, sg = s & 3;
            int row = m0 + m;
            float4 v = {0.f, 0.f, 0.f, 0.f};
            if (row < M) v = *(const float4*)(Abase + (size_t)row * 128 + kc + sg * 8);
            *(float4*)&As[m * 40 + sg * 8] = v;
        }
#pragma unroll
        for (int s = tid; s < 512; s += 256) {
            int n = s >> 2, sg = s & 3;
            *(float4*)&Bs[n * 40 + sg * 8] =
                *(const float4*)(WT + (size_t)(n0 + n) * 256 + k0 + sg * 8);
        }
        __syncthreads();

        short8 a[4], b[4];
#pragma unroll
        for (int i = 0; i < 4; ++i)
            a[i] = *(const short8*)&As[(wr * 64 + i * 16 + lane16) * 40 + q * 8];
#pragma unroll
        for (int j = 0; j < 4; ++j)
            b[j] = *(const short8*)&Bs[(wc * 64 + j * 16 + lane16) * 40 + q * 8];
#pragma unroll
        for (int i = 0; i < 4; ++i)
#pragma unroll
            for (int j = 0; j < 4; ++j)
                acc[i][j] = __builtin_amdgcn_mfma_f32_16x16x32_bf16(a[i], b[j], acc[i][j], 0, 0, 0);
        __syncthreads();
    }

#pragma unroll
    for (int i = 0; i < 4; ++i) {
#pragma unroll
        for (int r = 0; r < 4; ++r) {
            int row = m0 + wr * 64 + i * 16 + q * 4 + r;
            if (row >= M) continue;
#pragma unroll
            for (int j = 0; j < 4; ++j) {
                int col = n0 + wc * 64 + j * 16 + lane16;
                float v = fmaxf(acc[i][j][r] + bias[col], 0.f);
                H[(size_t)row * 256 + col] = f2b_rne(v);
            }
        }
    }
}

// ---------------- layer 2 MFMA GEMM ----------------

__global__ __launch_bounds__(256) void k_lin2_mfma(
        const unsigned short* __restrict__ A0, const unsigned short* __restrict__ A1,
        const unsigned short* __restrict__ WT, const float* __restrict__ bias,
        float* __restrict__ Z, int M) {
    __shared__ short As[128 * 40];
    __shared__ short Bs[32 * 40];

    int tid = threadIdx.x;
    int m0 = blockIdx.x * 128;
    int L = tid & 63, wv = tid >> 6;
    int lane16 = L & 15, q = L >> 4;

    f32x4 acc[2][2];
#pragma unroll
    for (int i = 0; i < 2; ++i)
#pragma unroll
        for (int j = 0; j < 2; ++j) acc[i][j] = (f32x4){0.f, 0.f, 0.f, 0.f};

    for (int k0 = 0; k0 < 512; k0 += 32) {
        const unsigned short* Abase = (k0 < 256) ? A0 : A1;
        int kc = k0 & 255;
#pragma unroll
        for (int s = tid; s < 512; s += 256) {
            int m = s >> 2, sg = s & 3;
            int row = m0 + m;
            float4 v = {0.f, 0.f, 0.f, 0.f};
            if (row < M) v = *(const float4*)(Abase + (size_t)row * 256 + kc + sg * 8);
            *(float4*)&As[m * 40 + sg * 8] = v;
        }
        if (tid < 128) {
            int n = tid >> 2, sg = tid & 3;
            *(float4*)&Bs[n * 40 + sg * 8] =
                *(const float4*)(WT + (size_t)n * 512 + k0 + sg * 8);
        }
        __syncthreads();

        short8 a[2], b[2];
#pragma unroll
        for (int i = 0; i < 2; ++i)
            a[i] = *(const short8*)&As[(wv * 32 + i * 16 + lane16) * 40 + q * 8];
#pragma unroll
        for (int j = 0; j < 2; ++j)
            b[j] = *(const short8*)&Bs[(j * 16 + lane16) * 40 + q * 8];
#pragma unroll
        for (int i = 0; i < 2; ++i)
#pragma unroll
            for (int j = 0; j < 2; ++j)
                acc[i][j] = __builtin_amdgcn_mfma_f32_16x16x32_bf16(a[i], b[j], acc[i][j], 0, 0, 0);
        __syncthreads();
    }

#pragma unroll
    for (int i = 0; i < 2; ++i) {
#pragma unroll
        for (int r = 0; r < 4; ++r) {
            int row = m0 + wv * 32 + i * 16 + q * 4 + r;
            if (row >= M) continue;
#pragma unroll
            for (int j = 0; j < 2; ++j) {
                int col = j * 16 + lane16;
                Z[(size_t)row * 32 + col] = acc[i][j][r] + bias[col];
            }
        }
    }
}

// ---------------- decode ----------------

__global__ void k_decode(const float* __restrict__ z, const int* __restrict__ eli,
                         int EL, float* __restrict__ out) {
    int tid = blockIdx.x * blockDim.x + threadIdx.x;
    int e = tid >> 3, lane = tid & 7;
    if (e >= EL) return;
    int s = eli[e], d = eli[EL + e];
    float4 a = *((const float4*)(z + (size_t)s * 32) + lane);
    float4 b = *((const float4*)(z + (size_t)d * 32) + lane);
    float dot = a.x * b.x + a.y * b.y + a.z * b.z + a.w * b.w;
    dot += __shfl_xor(dot, 1);
    dot += __shfl_xor(dot, 2);
    dot += __shfl_xor(dot, 4);
    if (lane == 0) out[e] = dot;
}

// ---------------- launch ----------------

extern "C" void kernel_launch(void* const* d_in, const int* in_sizes, int n_in,
                              void* d_out, int out_size, void* d_ws, size_t ws_size,
                              hipStream_t stream) {
    const float* x   = (const float*)d_in[0];
    const int*   ei  = (const int*)d_in[1];
    const int*   eli = (const int*)d_in[2];
    const float* W1l = (const float*)d_in[3];
    const float* b1  = (const float*)d_in[4];
    const float* W1r = (const float*)d_in[5];
    const float* W2l = (const float*)d_in[6];
    const float* b2  = (const float*)d_in[7];
    const float* W2r = (const float*)d_in[8];
    float* out = (float*)d_out;

    const int N  = N_NODES;
    const int E  = in_sizes[1] / 2;
    const int EL = in_sizes[2] / 2;
    const int* src = ei;
    const int* dst = ei + E;

    char* ws = (char*)d_ws;
    size_t off = 0;
    auto alloc = [&](size_t bytes) -> void* {
        void* p = ws + off;
        off += (bytes + 255) & ~(size_t)255;
        return p;
    };
    unsigned short* xb   = (unsigned short*)alloc((size_t)N * 128 * 2);
    unsigned short* aggb = (unsigned short*)alloc((size_t)N * 256 * 2);
    unsigned short* hb   = (unsigned short*)alloc((size_t)N * 256 * 2);
    float* zbuf          = (float*)alloc((size_t)N * 32 * 4);
    unsigned short* wt1  = (unsigned short*)alloc(256 * 256 * 2);
    unsigned short* wt2  = (unsigned short*)alloc(32 * 512 * 2);
    int* rowptr   = (int*)alloc((size_t)(N + 1) * 4);
    int* cursor   = (int*)alloc((size_t)(N + 256) * 4);   // cursor[N] + pub[256] contiguous
    int* pub      = cursor + N;
    int* esrc     = (int*)alloc((size_t)E * 4);

    const int tb = 256;
    const int nb = (N + 255) / 256;   // 196 blocks <= 256 CUs -> all co-resident

    // zero cursor (hist counters) + pub (scan lookback slots) in one memset
    hipMemsetAsync(cursor, 0, (size_t)(N + 256) * 4, stream);

    int prep_blocks = 6250 + 320 + (E + tb - 1) / tb;
    k_prep<<<prep_blocks, tb, 0, stream>>>(x, xb, W1l, W1r, wt1, W2l, W2r, wt2, dst, E, cursor);

    // single-pass scan -> rowptr + cursor, then scatter
    k_scan_fused<<<nb, 256, 0, stream>>>(cursor, rowptr, cursor, pub, N, E);
    k_scatter<<<(E + 8 * tb - 1) / (8 * tb), tb, 0, stream>>>(src, dst, E, cursor, esrc);

    // layer 1
    k_seg_max1<<<(N + 3) / 4, 256, 0, stream>>>(xb, rowptr, esrc, aggb);
    dim3 g1(2, (N + 127) / 128);
    k_lin1_mfma<<<g1, 256, 0, stream>>>(aggb, xb, wt1, b1, hb, N);

    // layer 2
    k_seg_max2<<<(N + 3) / 4, 256, 0, stream>>>(hb, rowptr, esrc, aggb);
    k_lin2_mfma<<<(N + 127) / 128, 256, 0, stream>>>(aggb, hb, wt2, b2, zbuf, N);

    // decode
    k_decode<<<(EL * 8 + 255) / 256, 256, 0, stream>>>(zbuf, eli, EL, out);
}

// Round 9
// 304.130 us; speedup vs baseline: 1.1378x; 1.1378x over previous
//
#include <hip/hip_runtime.h>
#include <hip/hip_bf16.h>
#include <math.h>

#define N_NODES 50000
#define NBKT 196        // dst buckets of 256 nodes (nb of the scan == NBKT)
#define BSH 8
#define TILE 8192       // edges per k_bin1 block
#define P2CAP 5888      // k_bin2 LDS staging capacity (mean 4081, +28 sigma)

typedef __attribute__((ext_vector_type(8))) short short8;   // 8 bf16 = 4 VGPRs
typedef __attribute__((ext_vector_type(4))) float f32x4;

static __device__ __forceinline__ float b2f(unsigned int u16) {
    union { unsigned int i; float f; } c; c.i = u16 << 16; return c.f;
}
static __device__ __forceinline__ unsigned int fbits(float f) {
    union { float f; unsigned int i; } c; c.f = f; return c.i;
}
static __device__ __forceinline__ unsigned short f2b_rne(float f) {
    unsigned int u = fbits(f);
    u += 0x7fff + ((u >> 16) & 1);
    return (unsigned short)(u >> 16);
}

// ---------------- fused prep: cast x, cast+transpose weights, histogram ----------------

__global__ __launch_bounds__(256) void k_prep(
        const float* __restrict__ x, unsigned short* __restrict__ xb,
        const float* __restrict__ W1l, const float* __restrict__ W1r, unsigned short* __restrict__ wt1,
        const float* __restrict__ W2l, const float* __restrict__ W2r, unsigned short* __restrict__ wt2,
        const int* __restrict__ dst, int E, int* __restrict__ counts) {
    const int CX = (N_NODES * 128 / 4) / 256;   // 6250
    int b = blockIdx.x, t = threadIdx.x;
    if (b < CX) {
        int i = b * 256 + t;
        float4 v = *(const float4*)(x + (size_t)i * 4);
        ushort4 o;
        o.x = f2b_rne(v.x); o.y = f2b_rne(v.y); o.z = f2b_rne(v.z); o.w = f2b_rne(v.w);
        *(ushort4*)(xb + (size_t)i * 4) = o;
    } else if (b < CX + 256) {
        int i = (b - CX) * 256 + t;             // 65536: WT1[n][k]
        int n = i >> 8, k = i & 255;
        float v = (k < 128) ? W1l[(size_t)k * 256 + n] : W1r[(size_t)(k - 128) * 256 + n];
        wt1[(size_t)n * 256 + k] = f2b_rne(v);
    } else if (b < CX + 320) {
        int i = (b - CX - 256) * 256 + t;       // 16384: WT2[n][k]
        int n = i >> 9, k = i & 511;
        float v = (k < 256) ? W2l[(size_t)k * 32 + n] : W2r[(size_t)(k - 256) * 32 + n];
        wt2[(size_t)n * 512 + k] = f2b_rne(v);
    } else {
        int e = (b - CX - 320) * 256 + t;
        if (e < E) atomicAdd(&counts[dst[e]], 1);
    }
}

// ---------------- single-pass exclusive scan (decoupled lookback) ----------------
// 196 blocks, all co-resident on 256 CUs. Also publishes bucket bases:
// block b's exclusive prefix IS rowptr[b*256] = bcur[b] (bucket b's tmp window base).

#define SCAN_FLAG 0x40000000

__global__ __launch_bounds__(256) void k_scan_fused(const int* __restrict__ counts,
        int* __restrict__ rowptr, int* __restrict__ pub, int* __restrict__ bcur,
        int n, int E) {
    __shared__ int tmp[256];
    __shared__ int pfx;
    int b = blockIdx.x, t = threadIdx.x;
    int i = b * 256 + t;
    int v = (i < n) ? counts[i] : 0;
    tmp[t] = v;
    __syncthreads();
    for (int off = 1; off < 256; off <<= 1) {
        int add = (t >= off) ? tmp[t - off] : 0;
        __syncthreads();
        tmp[t] += add;
        __syncthreads();
    }
    if (t == 255) atomicExch(&pub[b], SCAN_FLAG | tmp[255]);   // publish block total
    if (t < 64) {
        int acc = 0;
        for (int base = 0; base < b; base += 64) {
            int idx = base + t;
            if (idx < b) {
                int val;
                do { val = atomicOr(&pub[idx], 0); } while (!(val & SCAN_FLAG));
                acc += val & (SCAN_FLAG - 1);
            }
        }
#pragma unroll
        for (int off = 32; off >= 1; off >>= 1) acc += __shfl_xor(acc, off);
        if (t == 0) pfx = acc;
    }
    __syncthreads();
    int ex = pfx + tmp[t] - v;
    if (i < n) rowptr[i] = ex;
    if (i == 0) rowptr[n] = E;
    if (t == 0 && b < NBKT) bcur[b] = pfx;   // bucket base for k_bin1
}

// ---------------- binned scatter pass 1: tile -> bucket-sorted tmp ----------------
// LDS-bins an 8192-edge tile by dst>>8, claims per-bucket global chunks (1 atomic
// per bucket per block), streams out bucket-contiguous (src,dst) pairs (~340B runs).

__global__ __launch_bounds__(256) void k_bin1(const int* __restrict__ src,
        const int* __restrict__ dst, int E, int* __restrict__ bcur,
        uint2* __restrict__ tmp) {
    __shared__ int cnt[NBKT], sstart[NBKT], gbase[NBKT], lcur[NBKT];
    __shared__ int sc[256];
    __shared__ uint2 stage[TILE];
    int b = blockIdx.x, t = threadIdx.x;
    int e0 = b * TILE;
    int tilecnt = min(TILE, E - e0);
    if (tilecnt <= 0) return;
    for (int i = t; i < NBKT; i += 256) cnt[i] = 0;
    __syncthreads();
    for (int i = t; i < tilecnt; i += 256) {
        int d = __builtin_nontemporal_load(&dst[e0 + i]);
        atomicAdd(&cnt[d >> BSH], 1);
    }
    __syncthreads();
    // parallel exclusive scan of cnt (padded to 256)
    int cv = (t < NBKT) ? cnt[t] : 0;
    sc[t] = cv;
    __syncthreads();
    for (int off = 1; off < 256; off <<= 1) {
        int add = (t >= off) ? sc[t - off] : 0;
        __syncthreads();
        sc[t] += add;
        __syncthreads();
    }
    if (t < NBKT) {
        sstart[t] = sc[t] - cv;
        lcur[t] = sc[t] - cv;
        gbase[t] = (cv > 0) ? atomicAdd(&bcur[t], cv) : 0;
    }
    __syncthreads();
    for (int i = t; i < tilecnt; i += 256) {
        int d = __builtin_nontemporal_load(&dst[e0 + i]);
        int s = __builtin_nontemporal_load(&src[e0 + i]);
        int q = atomicAdd(&lcur[d >> BSH], 1);
        uint2 p; p.x = (unsigned)s; p.y = (unsigned)d;
        stage[q] = p;
    }
    __syncthreads();
    for (int i = t; i < tilecnt; i += 256) {
        uint2 p = stage[i];
        int bk = (int)(p.y >> BSH);
        tmp[gbase[bk] + (i - sstart[bk])] = p;
    }
}

// ---------------- binned scatter pass 2: bucket -> final esrc (LDS-staged) ----------------
// One block per bucket; window [rowptr[b*256], rowptr[(b+1)*256]) is exactly full.
// Random writes land in LDS; global flush is contiguous full lines.

__global__ __launch_bounds__(256) void k_bin2(const uint2* __restrict__ tmp,
        const int* __restrict__ rowptr, int* __restrict__ esrc, int N) {
    __shared__ int lcur[256];
    __shared__ int stage[P2CAP];
    int b = blockIdx.x, t = threadIdx.x;
    int d0 = b << BSH;
    int nd = min(256, N - d0);
    int wstart = rowptr[d0];
    int wend = rowptr[d0 + nd];
    int count = wend - wstart;
    if (t < nd) lcur[t] = rowptr[d0 + t] - wstart;
    __syncthreads();
    if (count <= P2CAP) {
        for (int i = t; i < count; i += 256) {
            uint2 p = tmp[wstart + i];
            int q = atomicAdd(&lcur[(int)p.y - d0], 1);
            stage[q] = (int)p.x;
        }
        __syncthreads();
        for (int i = t; i < count; i += 256)
            esrc[wstart + i] = stage[i];
    } else {
        // overflow fallback (statistically unreachable): direct global writes
        for (int i = t; i < count; i += 256) {
            uint2 p = tmp[wstart + i];
            int q = atomicAdd(&lcur[(int)p.y - d0], 1);
            esrc[wstart + q] = (int)p.x;
        }
    }
}

// ---------------- seg_max layer 1: uint4 gathers, 4 edges per load ----------------

__global__ __launch_bounds__(256) void k_seg_max1(const unsigned short* __restrict__ feat,
        const int* __restrict__ rowptr, const int* __restrict__ esrc,
        unsigned short* __restrict__ out) {
    int w = threadIdx.x >> 6, t = threadIdx.x & 63;
    int n = blockIdx.x * 4 + w;
    int lane16 = t & 15, sub = t >> 4;
    int beg = rowptr[n], end = rowptr[n + 1];
    float m[8];
#pragma unroll
    for (int k = 0; k < 8; ++k) m[k] = -INFINITY;
    for (int base = beg; base < end; base += 64) {
        int cnt = min(64, end - base);
        int vidx = (base + t < end) ? __builtin_nontemporal_load(&esrc[base + t]) : 0;
        for (int j = 0; j < cnt; j += 16) {
            uint4 v[4];
#pragma unroll
            for (int u = 0; u < 4; ++u) {
                int e = min(j + 4 * u + sub, cnt - 1);
                int s = __shfl(vidx, e);
                v[u] = *(const uint4*)(feat + (size_t)s * 128 + lane16 * 8);
            }
#pragma unroll
            for (int u = 0; u < 4; ++u) {
                m[0] = fmaxf(m[0], b2f(v[u].x & 0xffff));
                m[1] = fmaxf(m[1], b2f(v[u].x >> 16));
                m[2] = fmaxf(m[2], b2f(v[u].y & 0xffff));
                m[3] = fmaxf(m[3], b2f(v[u].y >> 16));
                m[4] = fmaxf(m[4], b2f(v[u].z & 0xffff));
                m[5] = fmaxf(m[5], b2f(v[u].z >> 16));
                m[6] = fmaxf(m[6], b2f(v[u].w & 0xffff));
                m[7] = fmaxf(m[7], b2f(v[u].w >> 16));
            }
        }
    }
#pragma unroll
    for (int k = 0; k < 8; ++k) {
        m[k] = fmaxf(m[k], __shfl_xor(m[k], 16));
        m[k] = fmaxf(m[k], __shfl_xor(m[k], 32));
        if (beg == end) m[k] = 0.f;
    }
    if (sub == 0) {
        uint4 p;
        p.x = (fbits(m[0]) >> 16) | (fbits(m[1]) & 0xffff0000u);
        p.y = (fbits(m[2]) >> 16) | (fbits(m[3]) & 0xffff0000u);
        p.z = (fbits(m[4]) >> 16) | (fbits(m[5]) & 0xffff0000u);
        p.w = (fbits(m[6]) >> 16) | (fbits(m[7]) & 0xffff0000u);
        *(uint4*)(out + (size_t)n * 128 + lane16 * 8) = p;
    }
}

// ---------------- seg_max layer 2: 8 uint4 gathers in flight ----------------

__global__ __launch_bounds__(256) void k_seg_max2(const unsigned short* __restrict__ feat,
        const int* __restrict__ rowptr, const int* __restrict__ esrc,
        unsigned short* __restrict__ out) {
    int w = threadIdx.x >> 6, t = threadIdx.x & 63;
    int n = blockIdx.x * 4 + w;
    int lane32 = t & 31, half = t >> 5;
    int beg = rowptr[n], end = rowptr[n + 1];
    float m[8];
#pragma unroll
    for (int k = 0; k < 8; ++k) m[k] = -INFINITY;
    for (int base = beg; base < end; base += 64) {
        int cnt = min(64, end - base);
        int vidx = (base + t < end) ? __builtin_nontemporal_load(&esrc[base + t]) : 0;
        for (int j = 0; j < cnt; j += 16) {
            uint4 v[8];
#pragma unroll
            for (int u = 0; u < 8; ++u) {
                int e = min(j + 2 * u + half, cnt - 1);
                int s = __shfl(vidx, e);
                v[u] = *(const uint4*)(feat + (size_t)s * 256 + lane32 * 8);
            }
#pragma unroll
            for (int u = 0; u < 8; ++u) {
                m[0] = fmaxf(m[0], b2f(v[u].x & 0xffff));
                m[1] = fmaxf(m[1], b2f(v[u].x >> 16));
                m[2] = fmaxf(m[2], b2f(v[u].y & 0xffff));
                m[3] = fmaxf(m[3], b2f(v[u].y >> 16));
                m[4] = fmaxf(m[4], b2f(v[u].z & 0xffff));
                m[5] = fmaxf(m[5], b2f(v[u].z >> 16));
                m[6] = fmaxf(m[6], b2f(v[u].w & 0xffff));
                m[7] = fmaxf(m[7], b2f(v[u].w >> 16));
            }
        }
    }
#pragma unroll
    for (int k = 0; k < 8; ++k) {
        m[k] = fmaxf(m[k], __shfl_xor(m[k], 32));
        if (beg == end) m[k] = 0.f;
    }
    if (half == 0) {
        uint4 p;
        p.x = (fbits(m[0]) >> 16) | (fbits(m[1]) & 0xffff0000u);
        p.y = (fbits(m[2]) >> 16) | (fbits(m[3]) & 0xffff0000u);
        p.z = (fbits(m[4]) >> 16) | (fbits(m[5]) & 0xffff0000u);
        p.w = (fbits(m[6]) >> 16) | (fbits(m[7]) & 0xffff0000u);
        *(uint4*)(out + (size_t)n * 256 + lane32 * 8) = p;
    }
}

// ---------------- layer 1 MFMA GEMM ----------------

__global__ __launch_bounds__(256) void k_lin1_mfma(
        const unsigned short* __restrict__ A0, const unsigned short* __restrict__ A1,
        const unsigned short* __restrict__ WT, const float* __restrict__ bias,
        unsigned short* __restrict__ H, int M) {
    __shared__ short As[128 * 40];
    __shared__ short Bs[128 * 40];

    int tid = threadIdx.x;
    int m0 = blockIdx.y * 128, n0 = blockIdx.x * 128;
    int L = tid & 63, wv = tid >> 6;
    int wr = wv >> 1, wc = wv & 1;
    int lane16 = L & 15, q = L >> 4;

    f32x4 acc[4][4];
#pragma unroll
    for (int i = 0; i < 4; ++i)
#pragma unroll
        for (int j = 0; j < 4; ++j) acc[i][j] = (f32x4){0.f, 0.f, 0.f, 0.f};

    for (int k0 = 0; k0 < 256; k0 += 32) {
        const unsigned short* Abase = (k0 < 128) ? A0 : A1;
        int kc = k0 & 127;
#pragma unroll
        for (int s = tid; s < 512; s += 256) {
            int m = s >> 2, sg = s & 3;
            int row = m0 + m;
            float4 v = {0.f, 0.f, 0.f, 0.f};
            if (row < M) v = *(const float4*)(Abase + (size_t)row * 128 + kc + sg * 8);
            *(float4*)&As[m * 40 + sg * 8] = v;
        }
#pragma unroll
        for (int s = tid; s < 512; s += 256) {
            int n = s >> 2, sg = s & 3;
            *(float4*)&Bs[n * 40 + sg * 8] =
                *(const float4*)(WT + (size_t)(n0 + n) * 256 + k0 + sg * 8);
        }
        __syncthreads();

        short8 a[4], b[4];
#pragma unroll
        for (int i = 0; i < 4; ++i)
            a[i] = *(const short8*)&As[(wr * 64 + i * 16 + lane16) * 40 + q * 8];
#pragma unroll
        for (int j = 0; j < 4; ++j)
            b[j] = *(const short8*)&Bs[(wc * 64 + j * 16 + lane16) * 40 + q * 8];
#pragma unroll
        for (int i = 0; i < 4; ++i)
#pragma unroll
            for (int j = 0; j < 4; ++j)
                acc[i][j] = __builtin_amdgcn_mfma_f32_16x16x32_bf16(a[i], b[j], acc[i][j], 0, 0, 0);
        __syncthreads();
    }

#pragma unroll
    for (int i = 0; i < 4; ++i) {
#pragma unroll
        for (int r = 0; r < 4; ++r) {
            int row = m0 + wr * 64 + i * 16 + q * 4 + r;
            if (row >= M) continue;
#pragma unroll
            for (int j = 0; j < 4; ++j) {
                int col = n0 + wc * 64 + j * 16 + lane16;
                float v = fmaxf(acc[i][j][r] + bias[col], 0.f);
                H[(size_t)row * 256 + col] = f2b_rne(v);
            }
        }
    }
}

// ---------------- layer 2 MFMA GEMM ----------------

__global__ __launch_bounds__(256) void k_lin2_mfma(
        const unsigned short* __restrict__ A0, const unsigned short* __restrict__ A1,
        const unsigned short* __restrict__ WT, const float* __restrict__ bias,
        float* __restrict__ Z, int M) {
    __shared__ short As[128 * 40];
    __shared__ short Bs[32 * 40];

    int tid = threadIdx.x;
    int m0 = blockIdx.x * 128;
    int L = tid & 63, wv = tid >> 6;
    int lane16 = L & 15, q = L >> 4;

    f32x4 acc[2][2];
#pragma unroll
    for (int i = 0; i < 2; ++i)
#pragma unroll
        for (int j = 0; j < 2; ++j) acc[i][j] = (f32x4){0.f, 0.f, 0.f, 0.f};

    for (int k0 = 0; k0 < 512; k0 += 32) {
        const unsigned short* Abase = (k0 < 256) ? A0 : A1;
        int kc = k0 & 255;
#pragma unroll
        for (int s = tid; s < 512; s += 256) {
            int m = s >> 2, sg = s & 3;
            int row = m0 + m;
            float4 v = {0.f, 0.f, 0.f, 0.f};
            if (row < M) v = *(const float4*)(Abase + (size_t)row * 256 + kc + sg * 8);
            *(float4*)&As[m * 40 + sg * 8] = v;
        }
        if (tid < 128) {
            int n = tid >> 2, sg = tid & 3;
            *(float4*)&Bs[n * 40 + sg * 8] =
                *(const float4*)(WT + (size_t)n * 512 + k0 + sg * 8);
        }
        __syncthreads();

        short8 a[2], b[2];
#pragma unroll
        for (int i = 0; i < 2; ++i)
            a[i] = *(const short8*)&As[(wv * 32 + i * 16 + lane16) * 40 + q * 8];
#pragma unroll
        for (int j = 0; j < 2; ++j)
            b[j] = *(const short8*)&Bs[(j * 16 + lane16) * 40 + q * 8];
#pragma unroll
        for (int i = 0; i < 2; ++i)
#pragma unroll
            for (int j = 0; j < 2; ++j)
                acc[i][j] = __builtin_amdgcn_mfma_f32_16x16x32_bf16(a[i], b[j], acc[i][j], 0, 0, 0);
        __syncthreads();
    }

#pragma unroll
    for (int i = 0; i < 2; ++i) {
#pragma unroll
        for (int r = 0; r < 4; ++r) {
            int row = m0 + wv * 32 + i * 16 + q * 4 + r;
            if (row >= M) continue;
#pragma unroll
            for (int j = 0; j < 2; ++j) {
                int col = j * 16 + lane16;
                Z[(size_t)row * 32 + col] = acc[i][j][r] + bias[col];
            }
        }
    }
}

// ---------------- decode ----------------

__global__ void k_decode(const float* __restrict__ z, const int* __restrict__ eli,
                         int EL, float* __restrict__ out) {
    int tid = blockIdx.x * blockDim.x + threadIdx.x;
    int e = tid >> 3, lane = tid & 7;
    if (e >= EL) return;
    int s = eli[e], d = eli[EL + e];
    float4 a = *((const float4*)(z + (size_t)s * 32) + lane);
    float4 b = *((const float4*)(z + (size_t)d * 32) + lane);
    float dot = a.x * b.x + a.y * b.y + a.z * b.z + a.w * b.w;
    dot += __shfl_xor(dot, 1);
    dot += __shfl_xor(dot, 2);
    dot += __shfl_xor(dot, 4);
    if (lane == 0) out[e] = dot;
}

// ---------------- launch ----------------

extern "C" void kernel_launch(void* const* d_in, const int* in_sizes, int n_in,
                              void* d_out, int out_size, void* d_ws, size_t ws_size,
                              hipStream_t stream) {
    const float* x   = (const float*)d_in[0];
    const int*   ei  = (const int*)d_in[1];
    const int*   eli = (const int*)d_in[2];
    const float* W1l = (const float*)d_in[3];
    const float* b1  = (const float*)d_in[4];
    const float* W1r = (const float*)d_in[5];
    const float* W2l = (const float*)d_in[6];
    const float* b2  = (const float*)d_in[7];
    const float* W2r = (const float*)d_in[8];
    float* out = (float*)d_out;

    const int N  = N_NODES;
    const int E  = in_sizes[1] / 2;
    const int EL = in_sizes[2] / 2;
    const int* src = ei;
    const int* dst = ei + E;

    char* ws = (char*)d_ws;
    size_t off = 0;
    auto alloc = [&](size_t bytes) -> void* {
        void* p = ws + off;
        off += (bytes + 255) & ~(size_t)255;
        return p;
    };
    unsigned short* xb   = (unsigned short*)alloc((size_t)N * 128 * 2);
    unsigned short* aggb = (unsigned short*)alloc((size_t)N * 256 * 2);
    unsigned short* hb   = (unsigned short*)alloc((size_t)N * 256 * 2);
    float* zbuf          = (float*)alloc((size_t)N * 32 * 4);
    unsigned short* wt1  = (unsigned short*)alloc(256 * 256 * 2);
    unsigned short* wt2  = (unsigned short*)alloc(32 * 512 * 2);
    int* rowptr   = (int*)alloc((size_t)(N + 1) * 4);
    int* counts   = (int*)alloc((size_t)(N + 512) * 4);   // counts[N] + pub[256] + bcur[256]
    int* pub      = counts + N;
    int* bcur     = counts + N + 256;
    int* esrc     = (int*)alloc((size_t)E * 4);
    // tmp pairs (6.4 MB) aliased onto aggb (25.6 MB): dead until seg_max1 writes it,
    // and k_bin2 completes before seg_max1 launches (stream-ordered).
    uint2* tmpp   = (uint2*)aggb;

    const int tb = 256;
    const int nb = (N + 255) / 256;   // 196 == NBKT

    // zero counts + pub (bcur is fully written by k_scan_fused)
    hipMemsetAsync(counts, 0, (size_t)(N + 256) * 4, stream);

    int prep_blocks = 6250 + 320 + (E + tb - 1) / tb;
    k_prep<<<prep_blocks, tb, 0, stream>>>(x, xb, W1l, W1r, wt1, W2l, W2r, wt2, dst, E, counts);

    // scan -> rowptr + bucket bases, then two-pass binned scatter
    k_scan_fused<<<nb, 256, 0, stream>>>(counts, rowptr, pub, bcur, N, E);
    k_bin1<<<(E + TILE - 1) / TILE, 256, 0, stream>>>(src, dst, E, bcur, tmpp);
    k_bin2<<<NBKT, 256, 0, stream>>>(tmpp, rowptr, esrc, N);

    // layer 1
    k_seg_max1<<<(N + 3) / 4, 256, 0, stream>>>(xb, rowptr, esrc, aggb);
    dim3 g1(2, (N + 127) / 128);
    k_lin1_mfma<<<g1, 256, 0, stream>>>(aggb, xb, wt1, b1, hb, N);

    // layer 2
    k_seg_max2<<<(N + 3) / 4, 256, 0, stream>>>(hb, rowptr, esrc, aggb);
    k_lin2_mfma<<<(N + 127) / 128, 256, 0, stream>>>(aggb, hb, wt2, b2, zbuf, N);

    // decode
    k_decode<<<(EL * 8 + 255) / 256, 256, 0, stream>>>(zbuf, eli, EL, out);
}